// Round 10
// baseline (308.533 us; speedup 1.0000x reference)
//
#include <hip/hip_runtime.h>
#include <hip/hip_bf16.h>

// Problem constants (from reference)
#define N_NODES   40000
#define N_EDGES   640000
#define F         128      // F_IN == HID == 128
#define N_GRAPHS  64
#define N_CLASSES 10

typedef short bf16x8 __attribute__((ext_vector_type(8)));
typedef float f32x4  __attribute__((ext_vector_type(4)));

// fp32 -> bf16 with round-to-nearest-even
__device__ __forceinline__ unsigned short f2bf(float f) {
    union { float f; unsigned u; } v; v.f = f;
    unsigned r = v.u + 0x7fffu + ((v.u >> 16) & 1u);
    return (unsigned short)(r >> 16);
}
__device__ __forceinline__ float bflo(unsigned u) { return __uint_as_float(u << 16); }
__device__ __forceinline__ float bfhi(unsigned u) { return __uint_as_float(u & 0xffff0000u); }
__device__ __forceinline__ unsigned pack2(float a, float b) {
    return (unsigned)f2bf(a) | ((unsigned)f2bf(b) << 16);
}

#define APITCH 136   // bf16 units; 272 B rows: 16B-aligned frags, bank-spread

// ---------------------------------------------------------------------------
// Precompute transposed bf16 weights: Wt_l[c][k] = bf16(W_l[k][c]), l=0..2.
// Fused: zero deg (for gemm1's degree count) and the two tickets.
__global__ void wcvt_kernel(const float* __restrict__ W1, const float* __restrict__ W2,
                            const float* __restrict__ W3, unsigned short* __restrict__ Wt,
                            int* __restrict__ deg, int* __restrict__ tks) {
    int idx = blockIdx.x * 256 + threadIdx.x;          // 0 .. 3*16384-1
    if (idx < N_NODES) deg[idx] = 0;
    if (idx < 2) tks[idx] = 0;
    int l = idx >> 14;
    int r = idx & 16383;
    int c = r >> 7, k = r & 127;
    const float* W = (l == 0) ? W1 : ((l == 1) ? W2 : W3);
    Wt[idx] = f2bf(W[k * 128 + c]);                    // write coalesced (k fast)
}

// ---------------------------------------------------------------------------
// CSR scan v3: 40 blocks x 1000 nodes. Per-block sum -> chunkSum -> ticket
// spin (40 blocks co-resident; GPU idle at dispatch since stream is serial)
// -> per-block base -> full-BW scan of own chunk. Also zeros pooled/cnt and
// computes dis[v] = rsqrt(deg[v]+1).
#define SCAN_BLOCKS 40
#define SCAN_CHUNK  1000
__global__ __launch_bounds__(256) void scan_kernel(
    const int* __restrict__ deg, int* __restrict__ rowptr,
    int* __restrict__ cursor, float* __restrict__ dis,
    float* __restrict__ pooled_zero, int* __restrict__ chunkSum,
    int* __restrict__ ticket) {
    __shared__ int wpart[4];
    __shared__ int blockBase;
    const int tid  = threadIdx.x;
    const int lane = tid & 63;
    const int wave = tid >> 6;
    const int b    = blockIdx.x;
    const int base = b * SCAN_CHUNK;

    // zero pooled (+cnt) cooperatively across all 40 blocks
    for (int k = b * 256 + tid; k < N_GRAPHS * F + N_GRAPHS; k += SCAN_BLOCKS * 256)
        pooled_zero[k] = 0.f;

    // 250 active threads x int4 = 1000 nodes
    int4 d = make_int4(0, 0, 0, 0);
    if (tid < 250) d = *(const int4*)(deg + base + tid * 4);
    const int sown = d.x + d.y + d.z + d.w;

    // inclusive wave scan
    int s = sown;
#pragma unroll
    for (int off = 1; off < 64; off <<= 1) {
        int n = __shfl_up(s, off, 64);
        if (lane >= off) s += n;
    }
    if (lane == 63) wpart[wave] = s;
    __syncthreads();

    if (tid == 0) {
        int run = 0;
#pragma unroll
        for (int w = 0; w < 4; ++w) { int t = wpart[w]; wpart[w] = run; run += t; }
        atomicExch(&chunkSum[b], run);        // block total, device-scope store
        __threadfence();
        atomicAdd(ticket, 1);
        while (atomicAdd(ticket, 0) < SCAN_BLOCKS) { }   // spin till all posted
        int bp = 0;
        for (int i = 0; i < b; ++i) bp += atomicAdd(&chunkSum[i], 0);
        blockBase = bp;
    }
    __syncthreads();

    if (tid < 250) {
        int excl = blockBase + wpart[wave] + (s - sown);
        int4 r;
        r.x = excl;
        r.y = r.x + d.x;
        r.z = r.y + d.y;
        r.w = r.z + d.z;
        *(int4*)(rowptr + base + tid * 4) = r;
        *(int4*)(cursor + base + tid * 4) = r;
        float4 di;
        di.x = rsqrtf((float)d.x + 1.0f);
        di.y = rsqrtf((float)d.y + 1.0f);
        di.z = rsqrtf((float)d.z + 1.0f);
        di.w = rsqrtf((float)d.w + 1.0f);
        *(float4*)(dis + base + tid * 4) = di;
    }
}

// CSR build step 3: csr_src[cursor[col[e]]++] = row[e]
__global__ void fill_kernel(const int* __restrict__ row, const int* __restrict__ col,
                            int* __restrict__ cursor, int* __restrict__ csr_src) {
    int e = blockIdx.x * 256 + threadIdx.x;
    if (e < N_EDGES) {
        int pos = atomicAdd(&cursor[col[e]], 1);
        csr_src[pos] = row[e];
    }
}

// ---------------------------------------------------------------------------
// MFMA GEMM: Hb[r][c] = bf16( scale_r * relu?(A[r][:] + bias) @ W )
// A is fp32 (ABF16=false, layer 1) or bf16 (ABF16=true, layers 2/3, = AGGb).
// Wt = precomputed W^T bf16 [128 c][128 k]. Block: 256 threads / 4 waves,
// 64 rows. LDS 52 KB -> 3 blocks/CU.
// Fragment maps (verified m89/m92/m120): A: m=lane&15, k=quad*8+j;
// B^T: n=lane&15, k=quad*8+j; D: col=lane&15, row=quad*4+reg.
// Epilogue: D -> As (wave-private rows, no barrier) -> coalesced uint4 stores.
template<bool ABF16, bool RELU, bool SCALE, bool COUNT>
__global__ __launch_bounds__(256) void gemm_mfma(
    const void* __restrict__ Araw, const unsigned short* __restrict__ Wt,
    const float* __restrict__ bias, const float* __restrict__ dis,
    unsigned short* __restrict__ Hb,
    const int* __restrict__ cnt_col, int* __restrict__ cnt_deg) {
    __shared__ unsigned short As[64 * APITCH];    // 17408 B
    __shared__ unsigned short Ws[128 * APITCH];   // 34816 B
    const int tid  = threadIdx.x;
    const int row0 = blockIdx.x * 64;

    if (COUNT) {   // fused degree count for CSR build (deg pre-zeroed)
        int t = (blockIdx.x * 256 + tid) * 4;
#pragma unroll
        for (int j = 0; j < 4; ++j) atomicAdd(&cnt_deg[cnt_col[t + j]], 1);
    }

    // Stage Wt (bf16, 32768 B = 2048 uint4) -> Ws
    {
        const uint4* src = (const uint4*)Wt;
#pragma unroll
        for (int j = 0; j < 8; ++j) {
            int c4 = tid + j * 256;        // 0..2047; 16 uint4 per 128-bf16 row
            int c  = c4 >> 4;
            int o  = c4 & 15;
            *(uint4*)(Ws + c * APITCH + o * 8) = src[c4];
        }
    }
    // Stage A -> bias/relu -> bf16 -> As
    if (ABF16) {
        const uint4* src = (const uint4*)Araw;     // 16 uint4 per 128-bf16 row
#pragma unroll
        for (int j = 0; j < 4; ++j) {
            int c4 = tid + j * 256;        // 0..1023
            int r  = c4 >> 4;
            int p  = c4 & 15;
            int o  = p << 3;               // bf16 col offset (8 per chunk)
            uint4 hv = src[(size_t)(row0 + r) * 16 + p];
            float f0 = bflo(hv.x), f1 = bfhi(hv.x), f2 = bflo(hv.y), f3 = bfhi(hv.y);
            float f4_ = bflo(hv.z), f5 = bfhi(hv.z), f6 = bflo(hv.w), f7 = bfhi(hv.w);
            if (bias) {
                float4 b0 = *(const float4*)(bias + o);
                float4 b1 = *(const float4*)(bias + o + 4);
                f0 += b0.x; f1 += b0.y; f2 += b0.z; f3 += b0.w;
                f4_ += b1.x; f5 += b1.y; f6 += b1.z; f7 += b1.w;
            }
            if (RELU) {
                f0 = fmaxf(f0, 0.f); f1 = fmaxf(f1, 0.f); f2 = fmaxf(f2, 0.f);
                f3 = fmaxf(f3, 0.f); f4_ = fmaxf(f4_, 0.f); f5 = fmaxf(f5, 0.f);
                f6 = fmaxf(f6, 0.f); f7 = fmaxf(f7, 0.f);
            }
            uint4 pk;
            pk.x = pack2(f0, f1); pk.y = pack2(f2, f3);
            pk.z = pack2(f4_, f5); pk.w = pack2(f6, f7);
            *(uint4*)(As + r * APITCH + o) = pk;
        }
    } else {
        const float* A = (const float*)Araw;
#pragma unroll
        for (int j = 0; j < 8; ++j) {
            int c4 = tid + j * 256;            // 0..2047; 32 float4 per row
            int r  = c4 >> 5;
            int o  = (c4 & 31) << 2;
            float4 v = *(const float4*)(A + (size_t)(row0 + r) * F + o);
            if (bias) {
                v.x += bias[o + 0]; v.y += bias[o + 1];
                v.z += bias[o + 2]; v.w += bias[o + 3];
            }
            if (RELU) {
                v.x = fmaxf(v.x, 0.f); v.y = fmaxf(v.y, 0.f);
                v.z = fmaxf(v.z, 0.f); v.w = fmaxf(v.w, 0.f);
            }
            uint2 p;
            p.x = pack2(v.x, v.y);
            p.y = pack2(v.z, v.w);
            *(uint2*)(As + r * APITCH + o) = p;
        }
    }
    __syncthreads();

    const int lane = tid & 63;
    const int wave = tid >> 6;
    const int m16  = lane & 15;
    const int quad = lane >> 4;

    f32x4 acc[8];
#pragma unroll
    for (int t = 0; t < 8; ++t) acc[t] = (f32x4)(0.0f);

#pragma unroll
    for (int ks = 0; ks < 128; ks += 32) {
        bf16x8 a = *(const bf16x8*)(As + (wave * 16 + m16) * APITCH + ks + quad * 8);
#pragma unroll
        for (int t = 0; t < 8; ++t) {
            bf16x8 b = *(const bf16x8*)(Ws + (t * 16 + m16) * APITCH + ks + quad * 8);
            acc[t] = __builtin_amdgcn_mfma_f32_16x16x32_bf16(a, b, acc[t], 0, 0, 0);
        }
    }

    // Epilogue: D row = quad*4+reg, col = t*16+m16; optional dis[row] scale.
    // Stage into As rows (wave-private) -> read back -> coalesced stores.
    const int rloc = wave * 16 + quad * 4;
    float sc[4];
#pragma unroll
    for (int rg = 0; rg < 4; ++rg) sc[rg] = SCALE ? dis[row0 + rloc + rg] : 1.0f;
#pragma unroll
    for (int t = 0; t < 8; ++t) {
        int col = t * 16 + m16;
#pragma unroll
        for (int rg = 0; rg < 4; ++rg)
            As[(rloc + rg) * APITCH + col] = f2bf(acc[t][rg] * sc[rg]);
    }
#pragma unroll
    for (int i = 0; i < 4; ++i) {
        int idx = lane + i * 64;          // 0..255
        int r   = idx >> 4;               // 0..15
        int p   = idx & 15;               // 16B chunk
        uint4 val = *(const uint4*)(As + (wave * 16 + r) * APITCH + p * 8);
        *((uint4*)(Hb + (size_t)(row0 + wave * 16 + r) * F) + p) = val;
    }
}

// ---------------------------------------------------------------------------
// Gather aggregation v5 (bf16 H -> bf16 AGG): one wave per node; 16 edges per
// step with 4 independent uint4 gathers in flight per lane; fp32 accumulate,
// quad shfl_xor reduction.
// SCALED=false: Hb pre-scaled by dis[row]:  AGG[v] = dis[v]*(sum Hb[src] + Hb[v])
// SCALED=true : AGG[v] = dis[v]*(sum dis[src]*Hb[src] + dis[v]*Hb[v])
template <bool SCALED>
__global__ __launch_bounds__(256) void gather_kernel(
    const unsigned short* __restrict__ Hb, const int* __restrict__ csr_src,
    const int* __restrict__ rowptr, const int* __restrict__ deg,
    const float* __restrict__ dis, unsigned short* __restrict__ AGGb) {
    const int gid  = blockIdx.x * 256 + threadIdx.x;
    const int v    = gid >> 6;
    if (v >= N_NODES) return;
    const int lane = threadIdx.x & 63;
    const int part = lane & 15;          // 16B chunk of the 256B row
    const int quad = lane >> 4;          // edge slot within group of 4

    const int start = rowptr[v];
    const int len   = deg[v];
    const uint4* Hp = (const uint4*)Hb + part;   // 16 uint4 per row

    float acc[8];
#pragma unroll
    for (int i = 0; i < 8; ++i) acc[i] = 0.f;

    for (int j0 = 0; j0 < len; j0 += 64) {
        int m = len - j0; if (m > 64) m = 64;
        int nidx = (lane < m) ? csr_src[start + j0 + lane] : 0;
        for (int j = 0; j < m; j += 16) {
            int   r[4];
            float w[4];
            uint4 h[4];
#pragma unroll
            for (int u = 0; u < 4; ++u) {
                int  sl    = j + u * 4 + quad;
                bool valid = sl < m;
                r[u] = __shfl(nidx, valid ? sl : 0, 64);
                w[u] = valid ? (SCALED ? dis[r[u]] : 1.0f) : 0.0f;
            }
#pragma unroll
            for (int u = 0; u < 4; ++u) h[u] = Hp[(size_t)r[u] * 16];
#pragma unroll
            for (int u = 0; u < 4; ++u) {
                acc[0] = fmaf(bflo(h[u].x), w[u], acc[0]);
                acc[1] = fmaf(bfhi(h[u].x), w[u], acc[1]);
                acc[2] = fmaf(bflo(h[u].y), w[u], acc[2]);
                acc[3] = fmaf(bfhi(h[u].y), w[u], acc[3]);
                acc[4] = fmaf(bflo(h[u].z), w[u], acc[4]);
                acc[5] = fmaf(bfhi(h[u].z), w[u], acc[5]);
                acc[6] = fmaf(bflo(h[u].w), w[u], acc[6]);
                acc[7] = fmaf(bfhi(h[u].w), w[u], acc[7]);
            }
        }
    }

#pragma unroll
    for (int i = 0; i < 8; ++i) {
        acc[i] += __shfl_xor(acc[i], 16, 64);
        acc[i] += __shfl_xor(acc[i], 32, 64);
    }

    if (quad == 0) {
        float dc  = dis[v];
        float ws_ = SCALED ? dc : 1.0f;
        uint4 h = Hp[(size_t)v * 16];               // self-loop
        acc[0] = fmaf(bflo(h.x), ws_, acc[0]); acc[1] = fmaf(bfhi(h.x), ws_, acc[1]);
        acc[2] = fmaf(bflo(h.y), ws_, acc[2]); acc[3] = fmaf(bfhi(h.y), ws_, acc[3]);
        acc[4] = fmaf(bflo(h.z), ws_, acc[4]); acc[5] = fmaf(bfhi(h.z), ws_, acc[5]);
        acc[6] = fmaf(bflo(h.w), ws_, acc[6]); acc[7] = fmaf(bfhi(h.w), ws_, acc[7]);
        uint4 pk;
        pk.x = pack2(acc[0] * dc, acc[1] * dc);
        pk.y = pack2(acc[2] * dc, acc[3] * dc);
        pk.z = pack2(acc[4] * dc, acc[5] * dc);
        pk.w = pack2(acc[6] * dc, acc[7] * dc);
        *((uint4*)AGGb + (size_t)v * 16 + part) = pk;
    }
}

// ---------------------------------------------------------------------------
// Pool v4 (bf16 AGG) + fused head via last-block ticket.
// 400 blocks x 100 nodes; 8 row-slots x 32 lanes x 4 cols; run-length flush.
// Last block (ticket) re-reads pooled/cnt via device-scope atomic reads and
// computes out = (pooled @ Wl)/cnt + bl.
#define POOL_NODES 100
__global__ __launch_bounds__(256) void pool_kernel(
    const unsigned short* __restrict__ AGGb, const int* __restrict__ batch,
    const float* __restrict__ b3, float* __restrict__ pooled,
    float* __restrict__ cnt, const float* __restrict__ Wl,
    const float* __restrict__ bl, float* __restrict__ out,
    int* __restrict__ ticket2) {
    __shared__ float plds[N_GRAPHS * F];   // 32 KB
    __shared__ float clds[N_GRAPHS];
    __shared__ int lastflag;
    const int tid  = threadIdx.x;
    const int f4   = (tid & 31) << 2;     // 4-col group
    const int slot = tid >> 5;            // 0..7
    const int base = blockIdx.x * POOL_NODES;
    const float4 bf = *(const float4*)(b3 + f4);

    float4 acc = make_float4(0.f, 0.f, 0.f, 0.f);
    float c = 0.f;
    int gcur = -1;
    for (int j = slot; j < POOL_NODES; j += 8) {
        int v = base + j;                 // 400*100 = 40000, always in range
        int g = batch[v];
        if (g != gcur) {
            if (gcur >= 0) {
                float* dst = pooled + gcur * F + f4;
                atomicAdd(dst + 0, acc.x); atomicAdd(dst + 1, acc.y);
                atomicAdd(dst + 2, acc.z); atomicAdd(dst + 3, acc.w);
                if (f4 == 0) atomicAdd(&cnt[gcur], c);
            }
            acc = make_float4(0.f, 0.f, 0.f, 0.f); c = 0.f; gcur = g;
        }
        uint2 a = *(const uint2*)(AGGb + (size_t)v * F + f4);
        acc.x += fmaxf(bflo(a.x) + bf.x, 0.f);
        acc.y += fmaxf(bfhi(a.x) + bf.y, 0.f);
        acc.z += fmaxf(bflo(a.y) + bf.z, 0.f);
        acc.w += fmaxf(bfhi(a.y) + bf.w, 0.f);
        c += 1.f;
    }
    if (gcur >= 0) {
        float* dst = pooled + gcur * F + f4;
        atomicAdd(dst + 0, acc.x); atomicAdd(dst + 1, acc.y);
        atomicAdd(dst + 2, acc.z); atomicAdd(dst + 3, acc.w);
        if (f4 == 0) atomicAdd(&cnt[gcur], c);
    }

    // --- last-block head ---
    __threadfence();                       // make this thread's atomics visible
    __syncthreads();                       // all threads of block posted
    if (tid == 0) {
        int old = atomicAdd(ticket2, 1);
        lastflag = (old == (int)gridDim.x - 1);
    }
    __syncthreads();
    if (!lastflag) return;

    // device-scope atomic reads (bypass L1) of pooled/cnt into LDS
    for (int k = tid; k < N_GRAPHS * F; k += 256)
        plds[k] = atomicAdd(&pooled[k], 0.f);
    if (tid < N_GRAPHS) clds[tid] = atomicAdd(&cnt[tid], 0.f);
    __syncthreads();

    for (int oidx = tid; oidx < N_GRAPHS * N_CLASSES; oidx += 256) {
        int g = oidx / N_CLASSES, cc = oidx % N_CLASSES;
        float a = 0.f;
        for (int f = 0; f < F; ++f)
            a += plds[g * F + f] * Wl[f * N_CLASSES + cc];
        out[oidx] = a / fmaxf(clds[g], 1.f) + bl[cc];
    }
}

// ---------------------------------------------------------------------------
extern "C" void kernel_launch(void* const* d_in, const int* in_sizes, int n_in,
                              void* d_out, int out_size, void* d_ws, size_t ws_size,
                              hipStream_t stream) {
    const float* x    = (const float*)d_in[0];
    const int*   ei   = (const int*)d_in[1];     // [2][E]
    const int*   bat  = (const int*)d_in[2];
    const float* W1   = (const float*)d_in[3];
    const float* b1   = (const float*)d_in[4];
    const float* W2   = (const float*)d_in[5];
    const float* b2   = (const float*)d_in[6];
    const float* W3   = (const float*)d_in[7];
    const float* b3   = (const float*)d_in[8];
    const float* Wl   = (const float*)d_in[9];
    const float* bl   = (const float*)d_in[10];
    float* out = (float*)d_out;

    const int* row = ei;                 // edge_index[0] (source)
    const int* col = ei + N_EDGES;       // edge_index[1] (target)

    // Workspace layout (16B-aligned chunks)
    float*          ws      = (float*)d_ws;
    float*          dis     = ws;                                     // 40000 f
    unsigned short* Hb      = (unsigned short*)(dis + N_NODES);       // 5.12M bf16
    unsigned short* AGGb    = Hb + (size_t)N_NODES * F;               // 5.12M bf16
    float*          pooled  = (float*)(AGGb + (size_t)N_NODES * F);   // 8192 f
    float*          cnt     = pooled + N_GRAPHS * F;                  // 64 f
    int*            deg     = (int*)(cnt + N_GRAPHS);                 // 40000 i
    int*            rowptr  = deg + N_NODES;                          // 40000 i
    int*            cursor  = rowptr + N_NODES;                       // 40000 i
    int*            csr_src = cursor + N_NODES;                       // 640000 i
    unsigned short* Wtb     = (unsigned short*)(csr_src + N_EDGES);   // 3*16384 bf16
    int*            chunkSum= (int*)(Wtb + 3 * 16384);                // 40 i
    int*            tks     = chunkSum + SCAN_BLOCKS;                 // 2 i

    const int edgeGrid   = (N_EDGES + 255) / 256;      // 2500
    const int gemmGrid   = N_NODES / 64;               // 625
    const int gatherGrid = (N_NODES * 64) / 256;       // 10000

    // --- W convert + zero deg/tickets (one kernel) ---
    wcvt_kernel<<<192, 256, 0, stream>>>(W1, W2, W3, Wtb, deg, tks);

    // --- layer 1 GEMM (unscaled bf16 H, fused degree count), then CSR build ---
    gemm_mfma<false, false, false, true><<<gemmGrid, 256, 0, stream>>>(
        x, Wtb, nullptr, nullptr, Hb, col, deg);
    scan_kernel<<<SCAN_BLOCKS, 256, 0, stream>>>(deg, rowptr, cursor, dis,
                                                 pooled, chunkSum, &tks[0]);
    fill_kernel<<<edgeGrid, 256, 0, stream>>>(row, col, cursor, csr_src);
    gather_kernel<true><<<gatherGrid, 256, 0, stream>>>(Hb, csr_src, rowptr, deg, dis, AGGb);

    // --- layer 2 (relu(agg+b1) fused into staging; H pre-scaled by dis) ---
    gemm_mfma<true, true, true, false><<<gemmGrid, 256, 0, stream>>>(
        AGGb, Wtb + 16384, b1, dis, Hb, nullptr, nullptr);
    gather_kernel<false><<<gatherGrid, 256, 0, stream>>>(Hb, csr_src, rowptr, deg, dis, AGGb);

    // --- layer 3 ---
    gemm_mfma<true, true, true, false><<<gemmGrid, 256, 0, stream>>>(
        AGGb, Wtb + 32768, b2, dis, Hb, nullptr, nullptr);
    gather_kernel<false><<<gatherGrid, 256, 0, stream>>>(Hb, csr_src, rowptr, deg, dis, AGGb);

    // --- pool (fuses relu(agg + b3)) + last-block head ---
    pool_kernel<<<N_NODES / POOL_NODES, 256, 0, stream>>>(
        AGGb, bat, b3, pooled, cnt, Wl, bl, out, &tks[1]);
}

// Round 11
// 294.073 us; speedup vs baseline: 1.0492x; 1.0492x over previous
//
#include <hip/hip_runtime.h>
#include <hip/hip_bf16.h>

// Problem constants (from reference)
#define N_NODES   40000
#define N_EDGES   640000
#define F         128      // F_IN == HID == 128
#define N_GRAPHS  64
#define N_CLASSES 10

typedef short bf16x8 __attribute__((ext_vector_type(8)));
typedef float f32x4  __attribute__((ext_vector_type(4)));

// fp32 -> bf16 with round-to-nearest-even
__device__ __forceinline__ unsigned short f2bf(float f) {
    union { float f; unsigned u; } v; v.f = f;
    unsigned r = v.u + 0x7fffu + ((v.u >> 16) & 1u);
    return (unsigned short)(r >> 16);
}
__device__ __forceinline__ float bflo(unsigned u) { return __uint_as_float(u << 16); }
__device__ __forceinline__ float bfhi(unsigned u) { return __uint_as_float(u & 0xffff0000u); }
__device__ __forceinline__ unsigned pack2(float a, float b) {
    return (unsigned)f2bf(a) | ((unsigned)f2bf(b) << 16);
}

#define APITCH 136   // bf16 units; 272 B rows: 16B-aligned frags, bank-spread

// ---------------------------------------------------------------------------
// Precompute transposed bf16 weights: Wt_l[c][k] = bf16(W_l[k][c]), l=0..2.
// Fused: zero deg (for gemm1's degree count) and the scan ticket.
__global__ void wcvt_kernel(const float* __restrict__ W1, const float* __restrict__ W2,
                            const float* __restrict__ W3, unsigned short* __restrict__ Wt,
                            int* __restrict__ deg, int* __restrict__ tks) {
    int idx = blockIdx.x * 256 + threadIdx.x;          // 0 .. 3*16384-1
    if (idx < N_NODES) deg[idx] = 0;
    if (idx < 2) tks[idx] = 0;
    int l = idx >> 14;
    int r = idx & 16383;
    int c = r >> 7, k = r & 127;
    const float* W = (l == 0) ? W1 : ((l == 1) ? W2 : W3);
    Wt[idx] = f2bf(W[k * 128 + c]);                    // write coalesced (k fast)
}

// ---------------------------------------------------------------------------
// CSR scan v3 (validated R10): 40 blocks x 1000 nodes. Per-block sum ->
// chunkSum -> ticket spin (40 blocks co-resident; GPU idle at dispatch since
// stream is serial) -> per-block base -> full-BW scan of own chunk. Also
// zeros pooled/cnt and computes dis[v] = rsqrt(deg[v]+1).
#define SCAN_BLOCKS 40
#define SCAN_CHUNK  1000
__global__ __launch_bounds__(256) void scan_kernel(
    const int* __restrict__ deg, int* __restrict__ rowptr,
    int* __restrict__ cursor, float* __restrict__ dis,
    float* __restrict__ pooled_zero, int* __restrict__ chunkSum,
    int* __restrict__ ticket) {
    __shared__ int wpart[4];
    __shared__ int blockBase;
    const int tid  = threadIdx.x;
    const int lane = tid & 63;
    const int wave = tid >> 6;
    const int b    = blockIdx.x;
    const int base = b * SCAN_CHUNK;

    // zero pooled (+cnt) cooperatively across all 40 blocks
    for (int k = b * 256 + tid; k < N_GRAPHS * F + N_GRAPHS; k += SCAN_BLOCKS * 256)
        pooled_zero[k] = 0.f;

    // 250 active threads x int4 = 1000 nodes
    int4 d = make_int4(0, 0, 0, 0);
    if (tid < 250) d = *(const int4*)(deg + base + tid * 4);
    const int sown = d.x + d.y + d.z + d.w;

    // inclusive wave scan
    int s = sown;
#pragma unroll
    for (int off = 1; off < 64; off <<= 1) {
        int n = __shfl_up(s, off, 64);
        if (lane >= off) s += n;
    }
    if (lane == 63) wpart[wave] = s;
    __syncthreads();

    if (tid == 0) {
        int run = 0;
#pragma unroll
        for (int w = 0; w < 4; ++w) { int t = wpart[w]; wpart[w] = run; run += t; }
        atomicExch(&chunkSum[b], run);        // block total, device-scope store
        __threadfence();
        atomicAdd(ticket, 1);
        while (atomicAdd(ticket, 0) < SCAN_BLOCKS) { }   // spin till all posted
        int bp = 0;
        for (int i = 0; i < b; ++i) bp += atomicAdd(&chunkSum[i], 0);
        blockBase = bp;
    }
    __syncthreads();

    if (tid < 250) {
        int excl = blockBase + wpart[wave] + (s - sown);
        int4 r;
        r.x = excl;
        r.y = r.x + d.x;
        r.z = r.y + d.y;
        r.w = r.z + d.z;
        *(int4*)(rowptr + base + tid * 4) = r;
        *(int4*)(cursor + base + tid * 4) = r;
        float4 di;
        di.x = rsqrtf((float)d.x + 1.0f);
        di.y = rsqrtf((float)d.y + 1.0f);
        di.z = rsqrtf((float)d.z + 1.0f);
        di.w = rsqrtf((float)d.w + 1.0f);
        *(float4*)(dis + base + tid * 4) = di;
    }
}

// CSR build step 3: csr_src[cursor[col[e]]++] = row[e]
__global__ void fill_kernel(const int* __restrict__ row, const int* __restrict__ col,
                            int* __restrict__ cursor, int* __restrict__ csr_src) {
    int e = blockIdx.x * 256 + threadIdx.x;
    if (e < N_EDGES) {
        int pos = atomicAdd(&cursor[col[e]], 1);
        csr_src[pos] = row[e];
    }
}

// ---------------------------------------------------------------------------
// MFMA GEMM: Hb[r][c] = bf16( scale_r * relu?(A[r][:] + bias) @ W )
// A is fp32 (ABF16=false, layer 1) or bf16 (ABF16=true, layers 2/3, = AGGb).
// Wt = precomputed W^T bf16 [128 c][128 k]. Block: 256 threads / 4 waves,
// 64 rows. LDS 52 KB -> 3 blocks/CU.
// Fragment maps (verified m89/m92/m120): A: m=lane&15, k=quad*8+j;
// B^T: n=lane&15, k=quad*8+j; D: col=lane&15, row=quad*4+reg.
// Epilogue: D -> As (wave-private rows, no barrier) -> coalesced uint4 stores.
template<bool ABF16, bool RELU, bool SCALE, bool COUNT>
__global__ __launch_bounds__(256) void gemm_mfma(
    const void* __restrict__ Araw, const unsigned short* __restrict__ Wt,
    const float* __restrict__ bias, const float* __restrict__ dis,
    unsigned short* __restrict__ Hb,
    const int* __restrict__ cnt_col, int* __restrict__ cnt_deg) {
    __shared__ unsigned short As[64 * APITCH];    // 17408 B
    __shared__ unsigned short Ws[128 * APITCH];   // 34816 B
    const int tid  = threadIdx.x;
    const int row0 = blockIdx.x * 64;

    if (COUNT) {   // fused degree count for CSR build (deg pre-zeroed)
        int t = (blockIdx.x * 256 + tid) * 4;
#pragma unroll
        for (int j = 0; j < 4; ++j) atomicAdd(&cnt_deg[cnt_col[t + j]], 1);
    }

    // Stage Wt (bf16, 32768 B = 2048 uint4) -> Ws
    {
        const uint4* src = (const uint4*)Wt;
#pragma unroll
        for (int j = 0; j < 8; ++j) {
            int c4 = tid + j * 256;        // 0..2047; 16 uint4 per 128-bf16 row
            int c  = c4 >> 4;
            int o  = c4 & 15;
            *(uint4*)(Ws + c * APITCH + o * 8) = src[c4];
        }
    }
    // Stage A -> bias/relu -> bf16 -> As
    if (ABF16) {
        const uint4* src = (const uint4*)Araw;     // 16 uint4 per 128-bf16 row
#pragma unroll
        for (int j = 0; j < 4; ++j) {
            int c4 = tid + j * 256;        // 0..1023
            int r  = c4 >> 4;
            int p  = c4 & 15;
            int o  = p << 3;               // bf16 col offset (8 per chunk)
            uint4 hv = src[(size_t)(row0 + r) * 16 + p];
            float f0 = bflo(hv.x), f1 = bfhi(hv.x), f2 = bflo(hv.y), f3 = bfhi(hv.y);
            float f4_ = bflo(hv.z), f5 = bfhi(hv.z), f6 = bflo(hv.w), f7 = bfhi(hv.w);
            if (bias) {
                float4 b0 = *(const float4*)(bias + o);
                float4 b1 = *(const float4*)(bias + o + 4);
                f0 += b0.x; f1 += b0.y; f2 += b0.z; f3 += b0.w;
                f4_ += b1.x; f5 += b1.y; f6 += b1.z; f7 += b1.w;
            }
            if (RELU) {
                f0 = fmaxf(f0, 0.f); f1 = fmaxf(f1, 0.f); f2 = fmaxf(f2, 0.f);
                f3 = fmaxf(f3, 0.f); f4_ = fmaxf(f4_, 0.f); f5 = fmaxf(f5, 0.f);
                f6 = fmaxf(f6, 0.f); f7 = fmaxf(f7, 0.f);
            }
            uint4 pk;
            pk.x = pack2(f0, f1); pk.y = pack2(f2, f3);
            pk.z = pack2(f4_, f5); pk.w = pack2(f6, f7);
            *(uint4*)(As + r * APITCH + o) = pk;
        }
    } else {
        const float* A = (const float*)Araw;
#pragma unroll
        for (int j = 0; j < 8; ++j) {
            int c4 = tid + j * 256;            // 0..2047; 32 float4 per row
            int r  = c4 >> 5;
            int o  = (c4 & 31) << 2;
            float4 v = *(const float4*)(A + (size_t)(row0 + r) * F + o);
            if (bias) {
                v.x += bias[o + 0]; v.y += bias[o + 1];
                v.z += bias[o + 2]; v.w += bias[o + 3];
            }
            if (RELU) {
                v.x = fmaxf(v.x, 0.f); v.y = fmaxf(v.y, 0.f);
                v.z = fmaxf(v.z, 0.f); v.w = fmaxf(v.w, 0.f);
            }
            uint2 p;
            p.x = pack2(v.x, v.y);
            p.y = pack2(v.z, v.w);
            *(uint2*)(As + r * APITCH + o) = p;
        }
    }
    __syncthreads();

    const int lane = tid & 63;
    const int wave = tid >> 6;
    const int m16  = lane & 15;
    const int quad = lane >> 4;

    f32x4 acc[8];
#pragma unroll
    for (int t = 0; t < 8; ++t) acc[t] = (f32x4)(0.0f);

#pragma unroll
    for (int ks = 0; ks < 128; ks += 32) {
        bf16x8 a = *(const bf16x8*)(As + (wave * 16 + m16) * APITCH + ks + quad * 8);
#pragma unroll
        for (int t = 0; t < 8; ++t) {
            bf16x8 b = *(const bf16x8*)(Ws + (t * 16 + m16) * APITCH + ks + quad * 8);
            acc[t] = __builtin_amdgcn_mfma_f32_16x16x32_bf16(a, b, acc[t], 0, 0, 0);
        }
    }

    // Epilogue: D row = quad*4+reg, col = t*16+m16; optional dis[row] scale.
    // Stage into As rows (wave-private) -> read back -> coalesced stores.
    const int rloc = wave * 16 + quad * 4;
    float sc[4];
#pragma unroll
    for (int rg = 0; rg < 4; ++rg) sc[rg] = SCALE ? dis[row0 + rloc + rg] : 1.0f;
#pragma unroll
    for (int t = 0; t < 8; ++t) {
        int col = t * 16 + m16;
#pragma unroll
        for (int rg = 0; rg < 4; ++rg)
            As[(rloc + rg) * APITCH + col] = f2bf(acc[t][rg] * sc[rg]);
    }
#pragma unroll
    for (int i = 0; i < 4; ++i) {
        int idx = lane + i * 64;          // 0..255
        int r   = idx >> 4;               // 0..15
        int p   = idx & 15;               // 16B chunk
        uint4 val = *(const uint4*)(As + (wave * 16 + r) * APITCH + p * 8);
        *((uint4*)(Hb + (size_t)(row0 + wave * 16 + r) * F) + p) = val;
    }
}

// ---------------------------------------------------------------------------
// Gather aggregation v5 (bf16 H -> bf16 AGG): one wave per node; 16 edges per
// step with 4 independent uint4 gathers in flight per lane; fp32 accumulate,
// quad shfl_xor reduction.
// SCALED=false: Hb pre-scaled by dis[row]:  AGG[v] = dis[v]*(sum Hb[src] + Hb[v])
// SCALED=true : AGG[v] = dis[v]*(sum dis[src]*Hb[src] + dis[v]*Hb[v])
template <bool SCALED>
__global__ __launch_bounds__(256) void gather_kernel(
    const unsigned short* __restrict__ Hb, const int* __restrict__ csr_src,
    const int* __restrict__ rowptr, const int* __restrict__ deg,
    const float* __restrict__ dis, unsigned short* __restrict__ AGGb) {
    const int gid  = blockIdx.x * 256 + threadIdx.x;
    const int v    = gid >> 6;
    if (v >= N_NODES) return;
    const int lane = threadIdx.x & 63;
    const int part = lane & 15;          // 16B chunk of the 256B row
    const int quad = lane >> 4;          // edge slot within group of 4

    const int start = rowptr[v];
    const int len   = deg[v];
    const uint4* Hp = (const uint4*)Hb + part;   // 16 uint4 per row

    float acc[8];
#pragma unroll
    for (int i = 0; i < 8; ++i) acc[i] = 0.f;

    for (int j0 = 0; j0 < len; j0 += 64) {
        int m = len - j0; if (m > 64) m = 64;
        int nidx = (lane < m) ? csr_src[start + j0 + lane] : 0;
        for (int j = 0; j < m; j += 16) {
            int   r[4];
            float w[4];
            uint4 h[4];
#pragma unroll
            for (int u = 0; u < 4; ++u) {
                int  sl    = j + u * 4 + quad;
                bool valid = sl < m;
                r[u] = __shfl(nidx, valid ? sl : 0, 64);
                w[u] = valid ? (SCALED ? dis[r[u]] : 1.0f) : 0.0f;
            }
#pragma unroll
            for (int u = 0; u < 4; ++u) h[u] = Hp[(size_t)r[u] * 16];
#pragma unroll
            for (int u = 0; u < 4; ++u) {
                acc[0] = fmaf(bflo(h[u].x), w[u], acc[0]);
                acc[1] = fmaf(bfhi(h[u].x), w[u], acc[1]);
                acc[2] = fmaf(bflo(h[u].y), w[u], acc[2]);
                acc[3] = fmaf(bfhi(h[u].y), w[u], acc[3]);
                acc[4] = fmaf(bflo(h[u].z), w[u], acc[4]);
                acc[5] = fmaf(bfhi(h[u].z), w[u], acc[5]);
                acc[6] = fmaf(bflo(h[u].w), w[u], acc[6]);
                acc[7] = fmaf(bfhi(h[u].w), w[u], acc[7]);
            }
        }
    }

#pragma unroll
    for (int i = 0; i < 8; ++i) {
        acc[i] += __shfl_xor(acc[i], 16, 64);
        acc[i] += __shfl_xor(acc[i], 32, 64);
    }

    if (quad == 0) {
        float dc  = dis[v];
        float ws_ = SCALED ? dc : 1.0f;
        uint4 h = Hp[(size_t)v * 16];               // self-loop
        acc[0] = fmaf(bflo(h.x), ws_, acc[0]); acc[1] = fmaf(bfhi(h.x), ws_, acc[1]);
        acc[2] = fmaf(bflo(h.y), ws_, acc[2]); acc[3] = fmaf(bfhi(h.y), ws_, acc[3]);
        acc[4] = fmaf(bflo(h.z), ws_, acc[4]); acc[5] = fmaf(bfhi(h.z), ws_, acc[5]);
        acc[6] = fmaf(bflo(h.w), ws_, acc[6]); acc[7] = fmaf(bfhi(h.w), ws_, acc[7]);
        uint4 pk;
        pk.x = pack2(acc[0] * dc, acc[1] * dc);
        pk.y = pack2(acc[2] * dc, acc[3] * dc);
        pk.z = pack2(acc[4] * dc, acc[5] * dc);
        pk.w = pack2(acc[6] * dc, acc[7] * dc);
        *((uint4*)AGGb + (size_t)v * 16 + part) = pk;
    }
}

// ---------------------------------------------------------------------------
// Pool v3 (validated R7-R9, no fence, no big LDS): 400 blocks x 100 nodes;
// 8 row-slots x 32 lanes x 4 cols. pooled[g][f] += relu(AGG[v][f] + b3[f]);
// cnt[g] += 1. batch sorted -> per-slot run-length accumulate, flush on change.
#define POOL_NODES 100
__global__ __launch_bounds__(256) void pool_kernel(
    const unsigned short* __restrict__ AGGb, const int* __restrict__ batch,
    const float* __restrict__ b3,
    float* __restrict__ pooled, float* __restrict__ cnt) {
    const int tid  = threadIdx.x;
    const int f4   = (tid & 31) << 2;     // 4-col group
    const int slot = tid >> 5;            // 0..7
    const int base = blockIdx.x * POOL_NODES;
    const float4 bf = *(const float4*)(b3 + f4);

    float4 acc = make_float4(0.f, 0.f, 0.f, 0.f);
    float c = 0.f;
    int gcur = -1;
    for (int j = slot; j < POOL_NODES; j += 8) {
        int v = base + j;                 // 400*100 = 40000, always in range
        int g = batch[v];
        if (g != gcur) {
            if (gcur >= 0) {
                float* dst = pooled + gcur * F + f4;
                atomicAdd(dst + 0, acc.x); atomicAdd(dst + 1, acc.y);
                atomicAdd(dst + 2, acc.z); atomicAdd(dst + 3, acc.w);
                if (f4 == 0) atomicAdd(&cnt[gcur], c);
            }
            acc = make_float4(0.f, 0.f, 0.f, 0.f); c = 0.f; gcur = g;
        }
        uint2 a = *(const uint2*)(AGGb + (size_t)v * F + f4);
        acc.x += fmaxf(bflo(a.x) + bf.x, 0.f);
        acc.y += fmaxf(bfhi(a.x) + bf.y, 0.f);
        acc.z += fmaxf(bflo(a.y) + bf.z, 0.f);
        acc.w += fmaxf(bfhi(a.y) + bf.w, 0.f);
        c += 1.f;
    }
    if (gcur >= 0) {
        float* dst = pooled + gcur * F + f4;
        atomicAdd(dst + 0, acc.x); atomicAdd(dst + 1, acc.y);
        atomicAdd(dst + 2, acc.z); atomicAdd(dst + 3, acc.w);
        if (f4 == 0) atomicAdd(&cnt[gcur], c);
    }
}

// ---------------------------------------------------------------------------
// Head: out[g][c] = (sum_f pooled[g][f] * Wl[f][c]) / max(cnt[g],1) + bl[c]
__global__ void head_kernel(const float* __restrict__ pooled,
                            const float* __restrict__ cnt,
                            const float* __restrict__ Wl,
                            const float* __restrict__ bl,
                            float* __restrict__ out) {
    int tid = threadIdx.x;
    if (tid >= N_GRAPHS * N_CLASSES) return;
    int g = tid / N_CLASSES, c = tid % N_CLASSES;
    float acc = 0.f;
    for (int ff = 0; ff < F; ++ff)
        acc += pooled[g * F + ff] * Wl[ff * N_CLASSES + c];
    out[g * N_CLASSES + c] = acc / fmaxf(cnt[g], 1.f) + bl[c];
}

// ---------------------------------------------------------------------------
extern "C" void kernel_launch(void* const* d_in, const int* in_sizes, int n_in,
                              void* d_out, int out_size, void* d_ws, size_t ws_size,
                              hipStream_t stream) {
    const float* x    = (const float*)d_in[0];
    const int*   ei   = (const int*)d_in[1];     // [2][E]
    const int*   bat  = (const int*)d_in[2];
    const float* W1   = (const float*)d_in[3];
    const float* b1   = (const float*)d_in[4];
    const float* W2   = (const float*)d_in[5];
    const float* b2   = (const float*)d_in[6];
    const float* W3   = (const float*)d_in[7];
    const float* b3   = (const float*)d_in[8];
    const float* Wl   = (const float*)d_in[9];
    const float* bl   = (const float*)d_in[10];
    float* out = (float*)d_out;

    const int* row = ei;                 // edge_index[0] (source)
    const int* col = ei + N_EDGES;       // edge_index[1] (target)

    // Workspace layout (16B-aligned chunks)
    float*          ws      = (float*)d_ws;
    float*          dis     = ws;                                     // 40000 f
    unsigned short* Hb      = (unsigned short*)(dis + N_NODES);       // 5.12M bf16
    unsigned short* AGGb    = Hb + (size_t)N_NODES * F;               // 5.12M bf16
    float*          pooled  = (float*)(AGGb + (size_t)N_NODES * F);   // 8192 f
    float*          cnt     = pooled + N_GRAPHS * F;                  // 64 f
    int*            deg     = (int*)(cnt + N_GRAPHS);                 // 40000 i
    int*            rowptr  = deg + N_NODES;                          // 40000 i
    int*            cursor  = rowptr + N_NODES;                       // 40000 i
    int*            csr_src = cursor + N_NODES;                       // 640000 i
    unsigned short* Wtb     = (unsigned short*)(csr_src + N_EDGES);   // 3*16384 bf16
    int*            chunkSum= (int*)(Wtb + 3 * 16384);                // 40 i
    int*            tks     = chunkSum + SCAN_BLOCKS;                 // 2 i

    const int edgeGrid   = (N_EDGES + 255) / 256;      // 2500
    const int gemmGrid   = N_NODES / 64;               // 625
    const int gatherGrid = (N_NODES * 64) / 256;       // 10000

    // --- W convert + zero deg/ticket (one kernel) ---
    wcvt_kernel<<<192, 256, 0, stream>>>(W1, W2, W3, Wtb, deg, tks);

    // --- layer 1 GEMM (unscaled bf16 H, fused degree count), then CSR build ---
    gemm_mfma<false, false, false, true><<<gemmGrid, 256, 0, stream>>>(
        x, Wtb, nullptr, nullptr, Hb, col, deg);
    scan_kernel<<<SCAN_BLOCKS, 256, 0, stream>>>(deg, rowptr, cursor, dis,
                                                 pooled, chunkSum, &tks[0]);
    fill_kernel<<<edgeGrid, 256, 0, stream>>>(row, col, cursor, csr_src);
    gather_kernel<true><<<gatherGrid, 256, 0, stream>>>(Hb, csr_src, rowptr, deg, dis, AGGb);

    // --- layer 2 (relu(agg+b1) fused into staging; H pre-scaled by dis) ---
    gemm_mfma<true, true, true, false><<<gemmGrid, 256, 0, stream>>>(
        AGGb, Wtb + 16384, b1, dis, Hb, nullptr, nullptr);
    gather_kernel<false><<<gatherGrid, 256, 0, stream>>>(Hb, csr_src, rowptr, deg, dis, AGGb);

    // --- layer 3 ---
    gemm_mfma<true, true, true, false><<<gemmGrid, 256, 0, stream>>>(
        AGGb, Wtb + 32768, b2, dis, Hb, nullptr, nullptr);
    gather_kernel<false><<<gatherGrid, 256, 0, stream>>>(Hb, csr_src, rowptr, deg, dis, AGGb);

    // --- pool (fuses relu(agg + b3)) + head ---
    pool_kernel<<<N_NODES / POOL_NODES, 256, 0, stream>>>(AGGb, bat, b3, pooled, cnt);
    head_kernel<<<1, N_GRAPHS * N_CLASSES, 0, stream>>>(pooled, cnt, Wl, bl, out);
}

// Round 12
// 293.987 us; speedup vs baseline: 1.0495x; 1.0003x over previous
//
#include <hip/hip_runtime.h>
#include <hip/hip_bf16.h>

// Problem constants (from reference)
#define N_NODES   40000
#define N_EDGES   640000
#define F         128      // F_IN == HID == 128
#define N_GRAPHS  64
#define N_CLASSES 10

typedef short bf16x8 __attribute__((ext_vector_type(8)));
typedef float f32x4  __attribute__((ext_vector_type(4)));

// fp32 -> bf16 with round-to-nearest-even
__device__ __forceinline__ unsigned short f2bf(float f) {
    union { float f; unsigned u; } v; v.f = f;
    unsigned r = v.u + 0x7fffu + ((v.u >> 16) & 1u);
    return (unsigned short)(r >> 16);
}
__device__ __forceinline__ float bflo(unsigned u) { return __uint_as_float(u << 16); }
__device__ __forceinline__ float bfhi(unsigned u) { return __uint_as_float(u & 0xffff0000u); }
__device__ __forceinline__ unsigned pack2(float a, float b) {
    return (unsigned)f2bf(a) | ((unsigned)f2bf(b) << 16);
}

#define APITCH 136   // bf16 units; 272 B rows: 16B-aligned frags, bank-spread

// ---------------------------------------------------------------------------
// Precompute transposed bf16 weights: Wt_l[c][k] = bf16(W_l[k][c]), l=0..2.
// Fused: zero deg (for gemm1's degree count) and the scan ticket.
__global__ void wcvt_kernel(const float* __restrict__ W1, const float* __restrict__ W2,
                            const float* __restrict__ W3, unsigned short* __restrict__ Wt,
                            int* __restrict__ deg, int* __restrict__ tks) {
    int idx = blockIdx.x * 256 + threadIdx.x;          // 0 .. 3*16384-1
    if (idx < N_NODES) deg[idx] = 0;
    if (idx < 2) tks[idx] = 0;
    int l = idx >> 14;
    int r = idx & 16383;
    int c = r >> 7, k = r & 127;
    const float* W = (l == 0) ? W1 : ((l == 1) ? W2 : W3);
    Wt[idx] = f2bf(W[k * 128 + c]);                    // write coalesced (k fast)
}

// ---------------------------------------------------------------------------
// CSR scan v3 (validated R10): 40 blocks x 1000 nodes. Per-block sum ->
// chunkSum -> ticket spin (40 blocks co-resident) -> per-block base ->
// full-BW scan of own chunk. Also zeros pooled/cnt and computes
// dis[v] = rsqrt(deg[v]+1).
#define SCAN_BLOCKS 40
#define SCAN_CHUNK  1000
__global__ __launch_bounds__(256) void scan_kernel(
    const int* __restrict__ deg, int* __restrict__ rowptr,
    int* __restrict__ cursor, float* __restrict__ dis,
    float* __restrict__ pooled_zero, int* __restrict__ chunkSum,
    int* __restrict__ ticket) {
    __shared__ int wpart[4];
    __shared__ int blockBase;
    const int tid  = threadIdx.x;
    const int lane = tid & 63;
    const int wave = tid >> 6;
    const int b    = blockIdx.x;
    const int base = b * SCAN_CHUNK;

    for (int k = b * 256 + tid; k < N_GRAPHS * F + N_GRAPHS; k += SCAN_BLOCKS * 256)
        pooled_zero[k] = 0.f;

    int4 d = make_int4(0, 0, 0, 0);
    if (tid < 250) d = *(const int4*)(deg + base + tid * 4);
    const int sown = d.x + d.y + d.z + d.w;

    int s = sown;
#pragma unroll
    for (int off = 1; off < 64; off <<= 1) {
        int n = __shfl_up(s, off, 64);
        if (lane >= off) s += n;
    }
    if (lane == 63) wpart[wave] = s;
    __syncthreads();

    if (tid == 0) {
        int run = 0;
#pragma unroll
        for (int w = 0; w < 4; ++w) { int t = wpart[w]; wpart[w] = run; run += t; }
        atomicExch(&chunkSum[b], run);
        __threadfence();
        atomicAdd(ticket, 1);
        while (atomicAdd(ticket, 0) < SCAN_BLOCKS) { }
        int bp = 0;
        for (int i = 0; i < b; ++i) bp += atomicAdd(&chunkSum[i], 0);
        blockBase = bp;
    }
    __syncthreads();

    if (tid < 250) {
        int excl = blockBase + wpart[wave] + (s - sown);
        int4 r;
        r.x = excl;
        r.y = r.x + d.x;
        r.z = r.y + d.y;
        r.w = r.z + d.z;
        *(int4*)(rowptr + base + tid * 4) = r;
        *(int4*)(cursor + base + tid * 4) = r;
        float4 di;
        di.x = rsqrtf((float)d.x + 1.0f);
        di.y = rsqrtf((float)d.y + 1.0f);
        di.z = rsqrtf((float)d.z + 1.0f);
        di.w = rsqrtf((float)d.w + 1.0f);
        *(float4*)(dis + base + tid * 4) = di;
    }
}

// CSR build step 3: csr_src[cursor[col[e]]++] = row[e]
__global__ void fill_kernel(const int* __restrict__ row, const int* __restrict__ col,
                            int* __restrict__ cursor, int* __restrict__ csr_src) {
    int e = blockIdx.x * 256 + threadIdx.x;
    if (e < N_EDGES) {
        int pos = atomicAdd(&cursor[col[e]], 1);
        csr_src[pos] = row[e];
    }
}

// ---------------------------------------------------------------------------
// MFMA GEMM v2: Hb[r][c] = bf16( scale_r * relu?(A[r][:] + bias) @ W )
// W^T staged in TWO 64-col halves: LDS = As 17KB + Ws-half 17KB = 34 KB
// -> 4 blocks/CU (was 3) for more cross-block latency hiding.
// Fragment maps (verified m89/m92/m120): A: m=lane&15, k=quad*8+j;
// B^T: n=lane&15, k=quad*8+j; D: col=lane&15, row=quad*4+reg.
// Epilogue: D -> As (wave-private rows, no barrier) -> coalesced uint4 stores.
template<bool ABF16, bool RELU, bool SCALE, bool COUNT>
__global__ __launch_bounds__(256) void gemm_mfma(
    const void* __restrict__ Araw, const unsigned short* __restrict__ Wt,
    const float* __restrict__ bias, const float* __restrict__ dis,
    unsigned short* __restrict__ Hb,
    const int* __restrict__ cnt_col, int* __restrict__ cnt_deg) {
    __shared__ unsigned short As[64 * APITCH];    // 17408 B
    __shared__ unsigned short Ws[64 * APITCH];    // 17408 B (one 64-col half)
    const int tid  = threadIdx.x;
    const int row0 = blockIdx.x * 64;

    if (COUNT) {   // fused degree count for CSR build (deg pre-zeroed)
        int t = (blockIdx.x * 256 + tid) * 4;
#pragma unroll
        for (int j = 0; j < 4; ++j) atomicAdd(&cnt_deg[cnt_col[t + j]], 1);
    }

    // Stage Ws half 0 (cols 0..63 of W^T; 1024 uint4)
    {
        const uint4* src = (const uint4*)Wt;
#pragma unroll
        for (int j = 0; j < 4; ++j) {
            int c4 = tid + j * 256;        // 0..1023; 16 uint4 per 128-bf16 row
            int c  = c4 >> 4;
            int o  = c4 & 15;
            *(uint4*)(Ws + c * APITCH + o * 8) = src[c4];
        }
    }
    // Stage A -> bias/relu -> bf16 -> As
    if (ABF16) {
        const uint4* src = (const uint4*)Araw;     // 16 uint4 per 128-bf16 row
#pragma unroll
        for (int j = 0; j < 4; ++j) {
            int c4 = tid + j * 256;        // 0..1023
            int r  = c4 >> 4;
            int p  = c4 & 15;
            int o  = p << 3;               // bf16 col offset (8 per chunk)
            uint4 hv = src[(size_t)(row0 + r) * 16 + p];
            float f0 = bflo(hv.x), f1 = bfhi(hv.x), f2 = bflo(hv.y), f3 = bfhi(hv.y);
            float f4_ = bflo(hv.z), f5 = bfhi(hv.z), f6 = bflo(hv.w), f7 = bfhi(hv.w);
            if (bias) {
                float4 b0 = *(const float4*)(bias + o);
                float4 b1 = *(const float4*)(bias + o + 4);
                f0 += b0.x; f1 += b0.y; f2 += b0.z; f3 += b0.w;
                f4_ += b1.x; f5 += b1.y; f6 += b1.z; f7 += b1.w;
            }
            if (RELU) {
                f0 = fmaxf(f0, 0.f); f1 = fmaxf(f1, 0.f); f2 = fmaxf(f2, 0.f);
                f3 = fmaxf(f3, 0.f); f4_ = fmaxf(f4_, 0.f); f5 = fmaxf(f5, 0.f);
                f6 = fmaxf(f6, 0.f); f7 = fmaxf(f7, 0.f);
            }
            uint4 pk;
            pk.x = pack2(f0, f1); pk.y = pack2(f2, f3);
            pk.z = pack2(f4_, f5); pk.w = pack2(f6, f7);
            *(uint4*)(As + r * APITCH + o) = pk;
        }
    } else {
        const float* A = (const float*)Araw;
#pragma unroll
        for (int j = 0; j < 8; ++j) {
            int c4 = tid + j * 256;            // 0..2047; 32 float4 per row
            int r  = c4 >> 5;
            int o  = (c4 & 31) << 2;
            float4 v = *(const float4*)(A + (size_t)(row0 + r) * F + o);
            if (bias) {
                v.x += bias[o + 0]; v.y += bias[o + 1];
                v.z += bias[o + 2]; v.w += bias[o + 3];
            }
            if (RELU) {
                v.x = fmaxf(v.x, 0.f); v.y = fmaxf(v.y, 0.f);
                v.z = fmaxf(v.z, 0.f); v.w = fmaxf(v.w, 0.f);
            }
            uint2 p;
            p.x = pack2(v.x, v.y);
            p.y = pack2(v.z, v.w);
            *(uint2*)(As + r * APITCH + o) = p;
        }
    }
    __syncthreads();

    const int lane = tid & 63;
    const int wave = tid >> 6;
    const int m16  = lane & 15;
    const int quad = lane >> 4;

    f32x4 acc[8];
#pragma unroll
    for (int t = 0; t < 8; ++t) acc[t] = (f32x4)(0.0f);

    // A fragments are reused across both halves — load once.
    bf16x8 afrag[4];
#pragma unroll
    for (int kk = 0; kk < 4; ++kk)
        afrag[kk] = *(const bf16x8*)(As + (wave * 16 + m16) * APITCH + kk * 32 + quad * 8);

    // --- half 0: output cols 0..63 (acc[0..3]) ---
#pragma unroll
    for (int kk = 0; kk < 4; ++kk) {
#pragma unroll
        for (int t = 0; t < 4; ++t) {
            bf16x8 b = *(const bf16x8*)(Ws + (t * 16 + m16) * APITCH + kk * 32 + quad * 8);
            acc[t] = __builtin_amdgcn_mfma_f32_16x16x32_bf16(afrag[kk], b, acc[t], 0, 0, 0);
        }
    }
    __syncthreads();   // all waves done reading Ws half 0

    // Stage Ws half 1 (cols 64..127)
    {
        const uint4* src = (const uint4*)Wt + 1024;
#pragma unroll
        for (int j = 0; j < 4; ++j) {
            int c4 = tid + j * 256;
            int c  = c4 >> 4;
            int o  = c4 & 15;
            *(uint4*)(Ws + c * APITCH + o * 8) = src[c4];
        }
    }
    __syncthreads();

    // --- half 1: output cols 64..127 (acc[4..7]) ---
#pragma unroll
    for (int kk = 0; kk < 4; ++kk) {
#pragma unroll
        for (int t = 0; t < 4; ++t) {
            bf16x8 b = *(const bf16x8*)(Ws + (t * 16 + m16) * APITCH + kk * 32 + quad * 8);
            acc[4 + t] = __builtin_amdgcn_mfma_f32_16x16x32_bf16(afrag[kk], b, acc[4 + t], 0, 0, 0);
        }
    }

    // Epilogue: D row = quad*4+reg, col = t*16+m16; optional dis[row] scale.
    // Stage into As rows (wave-private) -> read back -> coalesced stores.
    const int rloc = wave * 16 + quad * 4;
    float sc[4];
#pragma unroll
    for (int rg = 0; rg < 4; ++rg) sc[rg] = SCALE ? dis[row0 + rloc + rg] : 1.0f;
#pragma unroll
    for (int t = 0; t < 8; ++t) {
        int col = t * 16 + m16;
#pragma unroll
        for (int rg = 0; rg < 4; ++rg)
            As[(rloc + rg) * APITCH + col] = f2bf(acc[t][rg] * sc[rg]);
    }
#pragma unroll
    for (int i = 0; i < 4; ++i) {
        int idx = lane + i * 64;          // 0..255
        int r   = idx >> 4;               // 0..15
        int p   = idx & 15;               // 16B chunk
        uint4 val = *(const uint4*)(As + (wave * 16 + r) * APITCH + p * 8);
        *((uint4*)(Hb + (size_t)(row0 + wave * 16 + r) * F) + p) = val;
    }
}

// ---------------------------------------------------------------------------
// Gather aggregation v5 (bf16 H -> bf16 AGG): one wave per node; 16 edges per
// step with 4 independent uint4 gathers in flight per lane; fp32 accumulate,
// quad shfl_xor reduction.
// SCALED=false: Hb pre-scaled by dis[row]:  AGG[v] = dis[v]*(sum Hb[src] + Hb[v])
// SCALED=true : AGG[v] = dis[v]*(sum dis[src]*Hb[src] + dis[v]*Hb[v])
template <bool SCALED>
__global__ __launch_bounds__(256) void gather_kernel(
    const unsigned short* __restrict__ Hb, const int* __restrict__ csr_src,
    const int* __restrict__ rowptr, const int* __restrict__ deg,
    const float* __restrict__ dis, unsigned short* __restrict__ AGGb) {
    const int gid  = blockIdx.x * 256 + threadIdx.x;
    const int v    = gid >> 6;
    if (v >= N_NODES) return;
    const int lane = threadIdx.x & 63;
    const int part = lane & 15;          // 16B chunk of the 256B row
    const int quad = lane >> 4;          // edge slot within group of 4

    const int start = rowptr[v];
    const int len   = deg[v];
    const uint4* Hp = (const uint4*)Hb + part;   // 16 uint4 per row

    float acc[8];
#pragma unroll
    for (int i = 0; i < 8; ++i) acc[i] = 0.f;

    for (int j0 = 0; j0 < len; j0 += 64) {
        int m = len - j0; if (m > 64) m = 64;
        int nidx = (lane < m) ? csr_src[start + j0 + lane] : 0;
        for (int j = 0; j < m; j += 16) {
            int   r[4];
            float w[4];
            uint4 h[4];
#pragma unroll
            for (int u = 0; u < 4; ++u) {
                int  sl    = j + u * 4 + quad;
                bool valid = sl < m;
                r[u] = __shfl(nidx, valid ? sl : 0, 64);
                w[u] = valid ? (SCALED ? dis[r[u]] : 1.0f) : 0.0f;
            }
#pragma unroll
            for (int u = 0; u < 4; ++u) h[u] = Hp[(size_t)r[u] * 16];
#pragma unroll
            for (int u = 0; u < 4; ++u) {
                acc[0] = fmaf(bflo(h[u].x), w[u], acc[0]);
                acc[1] = fmaf(bfhi(h[u].x), w[u], acc[1]);
                acc[2] = fmaf(bflo(h[u].y), w[u], acc[2]);
                acc[3] = fmaf(bfhi(h[u].y), w[u], acc[3]);
                acc[4] = fmaf(bflo(h[u].z), w[u], acc[4]);
                acc[5] = fmaf(bfhi(h[u].z), w[u], acc[5]);
                acc[6] = fmaf(bflo(h[u].w), w[u], acc[6]);
                acc[7] = fmaf(bfhi(h[u].w), w[u], acc[7]);
            }
        }
    }

#pragma unroll
    for (int i = 0; i < 8; ++i) {
        acc[i] += __shfl_xor(acc[i], 16, 64);
        acc[i] += __shfl_xor(acc[i], 32, 64);
    }

    if (quad == 0) {
        float dc  = dis[v];
        float ws_ = SCALED ? dc : 1.0f;
        uint4 h = Hp[(size_t)v * 16];               // self-loop
        acc[0] = fmaf(bflo(h.x), ws_, acc[0]); acc[1] = fmaf(bfhi(h.x), ws_, acc[1]);
        acc[2] = fmaf(bflo(h.y), ws_, acc[2]); acc[3] = fmaf(bfhi(h.y), ws_, acc[3]);
        acc[4] = fmaf(bflo(h.z), ws_, acc[4]); acc[5] = fmaf(bfhi(h.z), ws_, acc[5]);
        acc[6] = fmaf(bflo(h.w), ws_, acc[6]); acc[7] = fmaf(bfhi(h.w), ws_, acc[7]);
        uint4 pk;
        pk.x = pack2(acc[0] * dc, acc[1] * dc);
        pk.y = pack2(acc[2] * dc, acc[3] * dc);
        pk.z = pack2(acc[4] * dc, acc[5] * dc);
        pk.w = pack2(acc[6] * dc, acc[7] * dc);
        *((uint4*)AGGb + (size_t)v * 16 + part) = pk;
    }
}

// ---------------------------------------------------------------------------
// Pool v3 (validated): 400 blocks x 100 nodes; 8 row-slots x 32 lanes x 4 cols.
// pooled[g][f] += relu(AGG[v][f] + b3[f]); cnt[g] += 1. batch sorted ->
// per-slot run-length accumulate, flush on change.
#define POOL_NODES 100
__global__ __launch_bounds__(256) void pool_kernel(
    const unsigned short* __restrict__ AGGb, const int* __restrict__ batch,
    const float* __restrict__ b3,
    float* __restrict__ pooled, float* __restrict__ cnt) {
    const int tid  = threadIdx.x;
    const int f4   = (tid & 31) << 2;     // 4-col group
    const int slot = tid >> 5;            // 0..7
    const int base = blockIdx.x * POOL_NODES;
    const float4 bf = *(const float4*)(b3 + f4);

    float4 acc = make_float4(0.f, 0.f, 0.f, 0.f);
    float c = 0.f;
    int gcur = -1;
    for (int j = slot; j < POOL_NODES; j += 8) {
        int v = base + j;                 // 400*100 = 40000, always in range
        int g = batch[v];
        if (g != gcur) {
            if (gcur >= 0) {
                float* dst = pooled + gcur * F + f4;
                atomicAdd(dst + 0, acc.x); atomicAdd(dst + 1, acc.y);
                atomicAdd(dst + 2, acc.z); atomicAdd(dst + 3, acc.w);
                if (f4 == 0) atomicAdd(&cnt[gcur], c);
            }
            acc = make_float4(0.f, 0.f, 0.f, 0.f); c = 0.f; gcur = g;
        }
        uint2 a = *(const uint2*)(AGGb + (size_t)v * F + f4);
        acc.x += fmaxf(bflo(a.x) + bf.x, 0.f);
        acc.y += fmaxf(bfhi(a.x) + bf.y, 0.f);
        acc.z += fmaxf(bflo(a.y) + bf.z, 0.f);
        acc.w += fmaxf(bfhi(a.y) + bf.w, 0.f);
        c += 1.f;
    }
    if (gcur >= 0) {
        float* dst = pooled + gcur * F + f4;
        atomicAdd(dst + 0, acc.x); atomicAdd(dst + 1, acc.y);
        atomicAdd(dst + 2, acc.z); atomicAdd(dst + 3, acc.w);
        if (f4 == 0) atomicAdd(&cnt[gcur], c);
    }
}

// ---------------------------------------------------------------------------
// Head: out[g][c] = (sum_f pooled[g][f] * Wl[f][c]) / max(cnt[g],1) + bl[c]
__global__ void head_kernel(const float* __restrict__ pooled,
                            const float* __restrict__ cnt,
                            const float* __restrict__ Wl,
                            const float* __restrict__ bl,
                            float* __restrict__ out) {
    int tid = threadIdx.x;
    if (tid >= N_GRAPHS * N_CLASSES) return;
    int g = tid / N_CLASSES, c = tid % N_CLASSES;
    float acc = 0.f;
    for (int ff = 0; ff < F; ++ff)
        acc += pooled[g * F + ff] * Wl[ff * N_CLASSES + c];
    out[g * N_CLASSES + c] = acc / fmaxf(cnt[g], 1.f) + bl[c];
}

// ---------------------------------------------------------------------------
extern "C" void kernel_launch(void* const* d_in, const int* in_sizes, int n_in,
                              void* d_out, int out_size, void* d_ws, size_t ws_size,
                              hipStream_t stream) {
    const float* x    = (const float*)d_in[0];
    const int*   ei   = (const int*)d_in[1];     // [2][E]
    const int*   bat  = (const int*)d_in[2];
    const float* W1   = (const float*)d_in[3];
    const float* b1   = (const float*)d_in[4];
    const float* W2   = (const float*)d_in[5];
    const float* b2   = (const float*)d_in[6];
    const float* W3   = (const float*)d_in[7];
    const float* b3   = (const float*)d_in[8];
    const float* Wl   = (const float*)d_in[9];
    const float* bl   = (const float*)d_in[10];
    float* out = (float*)d_out;

    const int* row = ei;                 // edge_index[0] (source)
    const int* col = ei + N_EDGES;       // edge_index[1] (target)

    // Workspace layout (16B-aligned chunks)
    float*          ws      = (float*)d_ws;
    float*          dis     = ws;                                     // 40000 f
    unsigned short* Hb      = (unsigned short*)(dis + N_NODES);       // 5.12M bf16
    unsigned short* AGGb    = Hb + (size_t)N_NODES * F;               // 5.12M bf16
    float*          pooled  = (float*)(AGGb + (size_t)N_NODES * F);   // 8192 f
    float*          cnt     = pooled + N_GRAPHS * F;                  // 64 f
    int*            deg     = (int*)(cnt + N_GRAPHS);                 // 40000 i
    int*            rowptr  = deg + N_NODES;                          // 40000 i
    int*            cursor  = rowptr + N_NODES;                       // 40000 i
    int*            csr_src = cursor + N_NODES;                       // 640000 i
    unsigned short* Wtb     = (unsigned short*)(csr_src + N_EDGES);   // 3*16384 bf16
    int*            chunkSum= (int*)(Wtb + 3 * 16384);                // 40 i
    int*            tks     = chunkSum + SCAN_BLOCKS;                 // 2 i

    const int edgeGrid   = (N_EDGES + 255) / 256;      // 2500
    const int gemmGrid   = N_NODES / 64;               // 625
    const int gatherGrid = (N_NODES * 64) / 256;       // 10000

    // --- W convert + zero deg/ticket (one kernel) ---
    wcvt_kernel<<<192, 256, 0, stream>>>(W1, W2, W3, Wtb, deg, tks);

    // --- layer 1 GEMM (unscaled bf16 H, fused degree count), then CSR build ---
    gemm_mfma<false, false, false, true><<<gemmGrid, 256, 0, stream>>>(
        x, Wtb, nullptr, nullptr, Hb, col, deg);
    scan_kernel<<<SCAN_BLOCKS, 256, 0, stream>>>(deg, rowptr, cursor, dis,
                                                 pooled, chunkSum, &tks[0]);
    fill_kernel<<<edgeGrid, 256, 0, stream>>>(row, col, cursor, csr_src);
    gather_kernel<true><<<gatherGrid, 256, 0, stream>>>(Hb, csr_src, rowptr, deg, dis, AGGb);

    // --- layer 2 (relu(agg+b1) fused into staging; H pre-scaled by dis) ---
    gemm_mfma<true, true, true, false><<<gemmGrid, 256, 0, stream>>>(
        AGGb, Wtb + 16384, b1, dis, Hb, nullptr, nullptr);
    gather_kernel<false><<<gatherGrid, 256, 0, stream>>>(Hb, csr_src, rowptr, deg, dis, AGGb);

    // --- layer 3 ---
    gemm_mfma<true, true, true, false><<<gemmGrid, 256, 0, stream>>>(
        AGGb, Wtb + 32768, b2, dis, Hb, nullptr, nullptr);
    gather_kernel<false><<<gatherGrid, 256, 0, stream>>>(Hb, csr_src, rowptr, deg, dis, AGGb);

    // --- pool (fuses relu(agg + b3)) + head ---
    pool_kernel<<<N_NODES / POOL_NODES, 256, 0, stream>>>(AGGb, bat, b3, pooled, cnt);
    head_kernel<<<1, N_GRAPHS * N_CLASSES, 0, stream>>>(pooled, cnt, Wl, bl, out);
}